// Round 1
// baseline (119.349 us; speedup 1.0000x reference)
//
#include <hip/hip_runtime.h>

// Problem constants
#define N_FILTERS 1024
#define B_TOTAL   1024
#define IMG       64            // H = W = 64
#define PAD_DIM   70            // 64 + 2*3 padded image side
// Xt layout in d_ws: fp16 [8 bg][PAD_DIM*PAD_DIM pixels][128 batches]  (10 MB).
// bg-major: each XCD's hot slice (4900 px * 256 B = 1.25 MB) is CONTIGUOUS and
// pixel stride is 256 B, so the 10 column loads per window row fold into
// 13-bit immediate offsets (wc*256 <= 2304).
// Window consumed per filter: padded rows i..i+9, cols j..j+9 (pool floor mode
// discards conv row/col 6, so only a 10x10 slab of the 11x11 window is read).

typedef _Float16 half2_t __attribute__((ext_vector_type(2)));
typedef float    fvec2  __attribute__((ext_vector_type(2)));

// ---------------- prep 1: zero the padded border of Xt (compact grid) ----------------
// Border pixels: rows {0,1,2,67,68,69} full width (6*70=420) + rows 3..66 with
// cols {0,1,2,67,68,69} (64*6=384) -> 804 blocks, no predicated-off blocks.
__global__ void zero_border_kernel(_Float16* __restrict__ Xt) {
    int bid = blockIdx.x;                 // 0..803
    int r, c;
    if (bid < 420) {
        int r6 = bid / 70;                // 0..5
        c = bid - r6 * 70;
        r = (r6 < 3) ? r6 : r6 + 64;      // rows 0,1,2,67,68,69
    } else {
        int t = bid - 420;
        r = 3 + t / 6;
        int k = t - (t / 6) * 6;          // 0..5
        c = (k < 3) ? k : k + 64;         // cols 0,1,2,67,68,69
    }
    const size_t pp = (size_t)r * PAD_DIM + c;
    // 8 bg groups * 128 fp16 (256 B) each; 256 threads = 8 bg * 32 lanes * 8 B
    const int bg = threadIdx.x >> 5, l = threadIdx.x & 31;
    unsigned long long* q = (unsigned long long*)Xt
        + (size_t)bg * (4900ull * 32) + pp * 32 + l;
    *q = 0ull;
}

// ---------------- prep 2: transpose X [1024 b][4096 p] -> Xt fp16 bg-major ----------------
__global__ __launch_bounds__(256) void transpose_kernel(
    const float* __restrict__ X, _Float16* __restrict__ Xt)
{
    __shared__ float T[64 * 65];         // [b_local][p_local], stride 65 kills conflicts
    const int pt = blockIdx.x & 63;      // pixel tile (64 pixels)
    const int bt = blockIdx.x >> 6;      // batch tile (64 batches)
    const int tx = threadIdx.x & 63, ty = threadIdx.x >> 6;

    #pragma unroll
    for (int pass = 0; pass < 16; ++pass) {
        int bl = pass * 4 + ty;          // lanes: consecutive pixels -> coalesced read
        T[bl * 65 + tx] = X[(size_t)(bt * 64 + bl) * 4096 + pt * 64 + tx];
    }
    __syncthreads();
    #pragma unroll
    for (int pass = 0; pass < 16; ++pass) {
        int pl = pass * 4 + ty;
        int p  = pt * 64 + pl;
        int r  = p >> 6, c = p & 63;
        // batch b = bt*64+tx -> bg = bt>>1, inner = (bt&1)*64 + tx
        // lanes: consecutive batches -> contiguous 128 B fp16 write
        Xt[((size_t)(bt >> 1) * 4900 + (size_t)(r + 3) * PAD_DIM + (c + 3)) * 128
           + (bt & 1) * 64 + tx] = (_Float16)T[tx * 65 + pl];
    }
}

// ---------------- main: lanes = batch, wave = one filter, packed-f32 math ----------------
// Block = 4 waves -> filters fg*4..fg*4+3, batches bg*128..bg*128+127 (2/lane via half2).
// Column-sliding inner loop: one live input pair instead of 10 -> ~18 fewer VGPRs,
// enabling 4 blocks/CU (16 waves/CU) for latency hiding.
__global__ __launch_bounds__(256, 4) void filters_main(
    const half2_t* __restrict__ Xt2,   // [8 bg][4900 px][64 half2]
    const float*   __restrict__ W,     // [F][25]
    const float*   __restrict__ bias,  // [F]
    const int*     __restrict__ pos,   // [F][2]
    float4*        __restrict__ out4)  // [B][1024 float4]  (= [B][F*4] floats)
{
    const int t    = threadIdx.x;
    const int lane = t & 63;
    const int w    = t >> 6;                       // wave id 0..3
    const int bg   = blockIdx.x & 7;               // batch group (128 batches) -> XCD pin
    const int fg   = blockIdx.x >> 3;              // filter group (4 filters)

    const int f  = fg * 4 + w;
    const int sf = __builtin_amdgcn_readfirstlane(f);
    const int si = __builtin_amdgcn_readfirstlane(pos[2 * sf]);       // row i, 0..59
    const int sj = __builtin_amdgcn_readfirstlane(pos[2 * sf + 1]);   // col j, 0..59

    float wk[25];
    const float* wp = W + sf * 25;                 // scalar address -> s_load into SGPRs
    #pragma unroll
    for (int k = 0; k < 25; ++k) wk[k] = wp[k];

    const half2_t* Xg = Xt2 + (size_t)bg * (4900ull * 64) + lane;

    fvec2 acc[36];
    #pragma unroll
    for (int k = 0; k < 36; ++k) acc[k] = (fvec2)0.0f;

    #pragma unroll
    for (int wr = 0; wr < 10; ++wr) {
        const half2_t* rowp = Xg + (size_t)((si + wr) * PAD_DIM + sj) * 64;
        const int ylo = (wr > 4) ? (wr - 4) : 0;
        const int yhi = (wr < 5) ? wr : 5;
        #pragma unroll
        for (int wc = 0; wc < 10; ++wc) {
            // pixel stride is 64 half2 = 256 B -> imm offset wc*256
            half2_t h = rowp[wc * 64];             // 1 dword, lanes coalesced 256 B
            fvec2 v;
            v.x = (float)h.x;
            v.y = (float)h.y;
            const int xlo = (wc > 4) ? (wc - 4) : 0;
            const int xhi = (wc < 5) ? wc : 5;
            #pragma unroll
            for (int y = 0; y < 6; ++y) {
                if (y >= ylo && y <= yhi) {
                    const int r = wr - y;
                    #pragma unroll
                    for (int x = 0; x < 6; ++x) {
                        if (x >= xlo && x <= xhi) {
                            const int c = wc - x;
                            acc[y * 6 + x] = wk[r * 5 + c] * v + acc[y * 6 + x];
                        }
                    }
                }
            }
        }
    }

    // 3x3 maxpool (stride 3) over the 6x6 conv grid -> 2x2; bias after max
    const float bv = bias[sf];
    float4 oA, oB;
    {
        float mA[4], mB[4];
        #pragma unroll
        for (int py = 0; py < 2; ++py) {
            #pragma unroll
            for (int px = 0; px < 2; ++px) {
                fvec2 m = acc[(3 * py) * 6 + 3 * px];
                #pragma unroll
                for (int dy = 0; dy < 3; ++dy)
                    #pragma unroll
                    for (int dx = 0; dx < 3; ++dx) {
                        fvec2 v = acc[(3 * py + dy) * 6 + (3 * px + dx)];
                        m.x = fmaxf(m.x, v.x);
                        m.y = fmaxf(m.y, v.y);
                    }
                mA[py * 2 + px] = m.x + bv;
                mB[py * 2 + px] = m.y + bv;
            }
        }
        oA.x = mA[0]; oA.y = mA[1]; oA.z = mA[2]; oA.w = mA[3];
        oB.x = mB[0]; oB.y = mB[1]; oB.z = mB[2]; oB.w = mB[3];
    }

    // out[b][f*4 .. f*4+3] as one float4; waves 0..3 of this block fill the same
    // 64 B line (cols fg*16..fg*16+15) for each b -> merges in L2.
    const int b = bg * 128 + lane * 2;
    out4[(size_t)b * 1024 + f]       = oA;
    out4[(size_t)(b + 1) * 1024 + f] = oB;
}

extern "C" void kernel_launch(void* const* d_in, const int* in_sizes, int n_in,
                              void* d_out, int out_size, void* d_ws, size_t ws_size,
                              hipStream_t stream) {
    const float* X    = (const float*)d_in[0];
    const float* W    = (const float*)d_in[1];
    const float* bias = (const float*)d_in[2];
    const int*   pos  = (const int*)d_in[3];
    float4* out4 = (float4*)d_out;
    _Float16* Xt = (_Float16*)d_ws;        // 8*4900*128 fp16 = 10 MB

    zero_border_kernel<<<804, 256, 0, stream>>>(Xt);
    transpose_kernel<<<1024, 256, 0, stream>>>(X, Xt);
    filters_main<<<2048, 256, 0, stream>>>((const half2_t*)Xt, W, bias, pos, out4);
}